// Round 10
// baseline (293.680 us; speedup 1.0000x reference)
//
#include <hip/hip_runtime.h>
#include <hip/hip_bf16.h>

#define NN   100000
#define KNB  32
#define DIN  256
#define DOUT 128
#define CHUNKN 10000          // h rows per gather chunk (2.56 MB, L2-resident)
#define NCHUNK 10

typedef __attribute__((ext_vector_type(8))) short short8;    // 8 x bf16
typedef __attribute__((ext_vector_type(4))) float f32x4;     // 4 x f32
typedef __attribute__((ext_vector_type(4))) unsigned u32x4;  // 16 B
typedef __attribute__((ext_vector_type(2))) int i32x2;       // 8 B

// v_cvt_pk_bf16_f32: packs 2 f32 -> 2 bf16 (RTNE) in one VALU op (no builtin).
__device__ __forceinline__ unsigned pk2(float a, float b) {
    unsigned r;
    asm("v_cvt_pk_bf16_f32 %0, %1, %2" : "=v"(r) : "v"(a), "v"(b));
    return r;
}

__device__ __forceinline__ short8 cvt8(f32x4 a, f32x4 b) {
    u32x4 t;
    t[0] = pk2(a[0], a[1]);
    t[1] = pk2(a[2], a[3]);
    t[2] = pk2(b[0], b[1]);
    t[3] = pk2(b[2], b[3]);
    return __builtin_bit_cast(short8, t);
}

// async global->LDS, 16 B per lane. LDS dest is wave-uniform base + lane*16.
__device__ __forceinline__ void load_lds16(const float* g, float* l) {
    __builtin_amdgcn_global_load_lds(
        (const __attribute__((address_space(1))) void*)g,
        (__attribute__((address_space(3))) void*)l, 16, 0, 0);
}

// ---------------------------------------------------------------------------
// Kernel 0: W [DIN][DOUT] f32  ->  Wt [DOUT][DIN] bf16 (transposed + converted)
// ---------------------------------------------------------------------------
__global__ void wt_conv(const float* __restrict__ W, unsigned short* __restrict__ Wt) {
    int t = blockIdx.x * 256 + threadIdx.x;   // 0 .. 32767
    int d = t >> 8;                           // dout
    int k = t & 255;                          // din
    float v = W[(size_t)k * DOUT + d];
    Wt[t] = (unsigned short)(pk2(v, v) & 0xffffu);
}

// ---------------------------------------------------------------------------
// Kernel 1: h = relu(feats @ W + b), bf16 row-major [n][128].  (R8 version:
// block = 32 nodes x 4 waves; wave w owns douts [32w,32w+32) -> its 16 KB Wt
// slice lives in 64 VGPR loaded up-front; feats staged once into 32 KB LDS
// with 4x cross-wave reuse; one vmcnt(0)+barrier per block; both-sides XOR
// swizzle. ~40 µs inferred from totals.)
// ---------------------------------------------------------------------------
__global__ __launch_bounds__(256, 4) void gemm_relu(
        const float* __restrict__ feats, const unsigned short* __restrict__ Wt,
        const float* __restrict__ bias, unsigned short* __restrict__ h) {
    __shared__ float sf[32 * DIN];            // 32 KB: 32 node rows x 256 f32

    const int tid  = threadIdx.x;
    const int lane = tid & 63;
    const int w    = tid >> 6;                // wave = dout group
    const int l16  = lane & 15;
    const int lq   = lane >> 4;
    const int blockBase = blockIdx.x * 32;    // 3125 * 32 == 100000 exactly

    short8 afrag[2][8];
    const unsigned short* wp = Wt + (size_t)(w * 32 + l16) * DIN + lq * 8;
    #pragma unroll
    for (int m = 0; m < 2; ++m)
        #pragma unroll
        for (int ks = 0; ks < 8; ++ks)
            afrag[m][ks] = *(const short8*)(wp + m * 16 * DIN + ks * 32);

    #pragma unroll
    for (int it = 0; it < 8; ++it) {
        int row = it * 4 + w;
        int cd  = lane;
        int cs  = cd ^ (row & 7);             // inverse-swizzled global source
        load_lds16(feats + (size_t)(blockBase + row) * DIN + cs * 4,
                   sf + it * 1024 + tid * 4);
    }

    asm volatile("s_waitcnt vmcnt(0)" ::: "memory");
    __syncthreads();

    f32x4 acc[2][2];
    acc[0][0] = (f32x4)0.f; acc[0][1] = (f32x4)0.f;
    acc[1][0] = (f32x4)0.f; acc[1][1] = (f32x4)0.f;

    #pragma unroll
    for (int ks = 0; ks < 8; ++ks) {
        short8 bf0, bf1;
        {
            const float* rbase = sf + (size_t)l16 * DIN;
            f32x4 x0 = *(const f32x4*)(rbase + ((ks * 8 + 2 * lq)     ^ (l16 & 7)) * 4);
            f32x4 x1 = *(const f32x4*)(rbase + ((ks * 8 + 2 * lq + 1) ^ (l16 & 7)) * 4);
            bf0 = cvt8(x0, x1);
        }
        {
            const float* rbase = sf + (size_t)(16 + l16) * DIN;
            f32x4 x0 = *(const f32x4*)(rbase + ((ks * 8 + 2 * lq)     ^ (l16 & 7)) * 4);
            f32x4 x1 = *(const f32x4*)(rbase + ((ks * 8 + 2 * lq + 1) ^ (l16 & 7)) * 4);
            bf1 = cvt8(x0, x1);
        }
        #pragma unroll
        for (int m = 0; m < 2; ++m) {
            acc[m][0] = __builtin_amdgcn_mfma_f32_16x16x32_bf16(afrag[m][ks], bf0, acc[m][0], 0, 0, 0);
            acc[m][1] = __builtin_amdgcn_mfma_f32_16x16x32_bf16(afrag[m][ks], bf1, acc[m][1], 0, 0, 0);
        }
    }

    #pragma unroll
    for (int m = 0; m < 2; ++m) {
        int dbase = w * 32 + m * 16 + lq * 4;
        f32x4 bv = *(const f32x4*)(bias + dbase);
        #pragma unroll
        for (int nf = 0; nf < 2; ++nf) {
            int node = blockBase + nf * 16 + l16;
            f32x4 v = acc[m][nf];
            float v0 = fmaxf(v[0] + bv[0], 0.f);
            float v1 = fmaxf(v[1] + bv[1], 0.f);
            float v2 = fmaxf(v[2] + bv[2], 0.f);
            float v3 = fmaxf(v[3] + bv[3], 0.f);
            uint2 st = make_uint2(pk2(v0, v1), pk2(v2, v3));
            *(uint2*)(h + (size_t)node * DOUT + dbase) = st;
        }
    }
}

// ---------------------------------------------------------------------------
// Kernel 2: out[n] = mean_k h_bf16[edge[n][k]], CACHE-BLOCKED along h rows.
// Runtime loop over 10 chunks of 10000 h-rows (2.56 MB -> L2-resident per
// XCD). Edges (2/lane) + accumulators (5 batches x 8 f32) stay in NAMED
// registers across the loop. 1250 blocks (~4.9/CU) are ALL resident at ~80
// VGPR -> blocks sweep chunks in near-lockstep, giving every XCD one
// resident window at a time. Fill floor: 8 XCD x 25.6 MB = 204 MB (vs 343
// measured for the unblocked gather). Edge test (e-lo)<CHUNKN is uniform per
// 16-lane group -> clean exec-mask predication. KEEP() defeats hoisting of
// the 160 loop-invariant shfl results (would spill, R3 lesson).
// ---------------------------------------------------------------------------
__global__ __launch_bounds__(256) void gather_chunked(
        const int* __restrict__ edge, const unsigned short* __restrict__ h,
        float* __restrict__ out) {
    const int q = threadIdx.x & 15;
    const int g = threadIdx.x >> 4;           // node slot 0..15 within a batch
    const int nodeBase = blockIdx.x * 80;     // 1250 * 80 == 100000 exactly

    // Edges: batch b covers node nodeBase + b*16 + g; lane q holds edges 2q,2q+1.
    i32x2 e0 = *(const i32x2*)(edge + (size_t)(nodeBase +  0 + g) * KNB + q * 2);
    i32x2 e1 = *(const i32x2*)(edge + (size_t)(nodeBase + 16 + g) * KNB + q * 2);
    i32x2 e2 = *(const i32x2*)(edge + (size_t)(nodeBase + 32 + g) * KNB + q * 2);
    i32x2 e3 = *(const i32x2*)(edge + (size_t)(nodeBase + 48 + g) * KNB + q * 2);
    i32x2 e4 = *(const i32x2*)(edge + (size_t)(nodeBase + 64 + g) * KNB + q * 2);

    f32x4 lo0 = (f32x4)0.f, hi0 = (f32x4)0.f;
    f32x4 lo1 = (f32x4)0.f, hi1 = (f32x4)0.f;
    f32x4 lo2 = (f32x4)0.f, hi2 = (f32x4)0.f;
    f32x4 lo3 = (f32x4)0.f, hi3 = (f32x4)0.f;
    f32x4 lo4 = (f32x4)0.f, hi4 = (f32x4)0.f;

    // Defeat loop-invariant hoisting of shfl(e) values out of the chunk loop.
    #define KEEP(E) do { int a_ = (E)[0], b_ = (E)[1]; \
        asm volatile("" : "+v"(a_), "+v"(b_)); (E)[0] = a_; (E)[1] = b_; } while (0)

    #define GK(k, EE, LO, HI) do { \
        int e_ = ((k) < 16) ? __shfl((EE)[0], (k), 16) \
                            : __shfl((EE)[1], (k) - 16, 16); \
        if ((unsigned)(e_ - clo) < (unsigned)CHUNKN) { \
            u32x4 v_ = *(const u32x4*)(h + (size_t)e_ * DOUT + q * 8); \
            LO[0] += __uint_as_float(v_[0] << 16); \
            LO[1] += __uint_as_float(v_[0] & 0xffff0000u); \
            LO[2] += __uint_as_float(v_[1] << 16); \
            LO[3] += __uint_as_float(v_[1] & 0xffff0000u); \
            HI[0] += __uint_as_float(v_[2] << 16); \
            HI[1] += __uint_as_float(v_[2] & 0xffff0000u); \
            HI[2] += __uint_as_float(v_[3] << 16); \
            HI[3] += __uint_as_float(v_[3] & 0xffff0000u); \
        } } while (0)

    #define BATCH32(EE, LO, HI) do { \
        GK( 0, EE, LO, HI); GK( 1, EE, LO, HI); GK( 2, EE, LO, HI); GK( 3, EE, LO, HI); \
        GK( 4, EE, LO, HI); GK( 5, EE, LO, HI); GK( 6, EE, LO, HI); GK( 7, EE, LO, HI); \
        GK( 8, EE, LO, HI); GK( 9, EE, LO, HI); GK(10, EE, LO, HI); GK(11, EE, LO, HI); \
        GK(12, EE, LO, HI); GK(13, EE, LO, HI); GK(14, EE, LO, HI); GK(15, EE, LO, HI); \
        GK(16, EE, LO, HI); GK(17, EE, LO, HI); GK(18, EE, LO, HI); GK(19, EE, LO, HI); \
        GK(20, EE, LO, HI); GK(21, EE, LO, HI); GK(22, EE, LO, HI); GK(23, EE, LO, HI); \
        GK(24, EE, LO, HI); GK(25, EE, LO, HI); GK(26, EE, LO, HI); GK(27, EE, LO, HI); \
        GK(28, EE, LO, HI); GK(29, EE, LO, HI); GK(30, EE, LO, HI); GK(31, EE, LO, HI); \
    } while (0)

    #pragma unroll 1
    for (int c = 0; c < NCHUNK; ++c) {
        const int clo = c * CHUNKN;
        KEEP(e0); KEEP(e1); KEEP(e2); KEEP(e3); KEEP(e4);
        BATCH32(e0, lo0, hi0);
        BATCH32(e1, lo1, hi1);
        BATCH32(e2, lo2, hi2);
        BATCH32(e3, lo3, hi3);
        BATCH32(e4, lo4, hi4);
    }

    #undef BATCH32
    #undef GK
    #undef KEEP

    const float sc = 1.f / KNB;
    #define STORE(B, LO, HI) do { \
        float* op_ = out + (size_t)(nodeBase + (B) * 16 + g) * DOUT + q * 8; \
        f32x4 o0_ = { LO[0] * sc, LO[1] * sc, LO[2] * sc, LO[3] * sc }; \
        f32x4 o1_ = { HI[0] * sc, HI[1] * sc, HI[2] * sc, HI[3] * sc }; \
        __builtin_nontemporal_store(o0_, (f32x4*)op_); \
        __builtin_nontemporal_store(o1_, (f32x4*)(op_ + 4)); } while (0)

    STORE(0, lo0, hi0);
    STORE(1, lo1, hi1);
    STORE(2, lo2, hi2);
    STORE(3, lo3, hi3);
    STORE(4, lo4, hi4);
    #undef STORE
}

// ---------------------------------------------------------------------------
extern "C" void kernel_launch(void* const* d_in, const int* in_sizes, int n_in,
                              void* d_out, int out_size, void* d_ws, size_t ws_size,
                              hipStream_t stream) {
    const float* feats = (const float*)d_in[0];   // [100000,256] f32
    const int*   edge  = (const int*)d_in[1];     // [100000,32] i32
    const float* W     = (const float*)d_in[2];   // [256,128] f32
    const float* b     = (const float*)d_in[3];   // [128] f32
    float* out = (float*)d_out;                   // [100000,128] f32

    unsigned short* Wt = (unsigned short*)d_ws;                    // 64 KB
    unsigned short* h  = (unsigned short*)((char*)d_ws + 65536);   // 25.6 MB row-major

    wt_conv<<<128, 256, 0, stream>>>(W, Wt);
    gemm_relu<<<NN / 32, 256, 0, stream>>>(feats, Wt, b, h);
    gather_chunked<<<NN / 80, 256, 0, stream>>>(edge, h, out);
}

// Round 11
// 232.131 us; speedup vs baseline: 1.2651x; 1.2651x over previous
//
#include <hip/hip_runtime.h>
#include <hip/hip_bf16.h>

#define NN   100000
#define KNB  32
#define DIN  256
#define DOUT 128
#define CHUNKN 10000          // h rows per gather chunk (2.56 MB, L2-resident; R10-proven)
#define NCHUNK 10

typedef __attribute__((ext_vector_type(8))) short short8;    // 8 x bf16
typedef __attribute__((ext_vector_type(4))) float f32x4;     // 4 x f32
typedef __attribute__((ext_vector_type(4))) unsigned u32x4;  // 16 B
typedef __attribute__((ext_vector_type(4))) int i32x4;       // 16 B
typedef __attribute__((ext_vector_type(2))) int i32x2;       // 8 B

// v_cvt_pk_bf16_f32: packs 2 f32 -> 2 bf16 (RTNE) in one VALU op (no builtin).
__device__ __forceinline__ unsigned pk2(float a, float b) {
    unsigned r;
    asm("v_cvt_pk_bf16_f32 %0, %1, %2" : "=v"(r) : "v"(a), "v"(b));
    return r;
}

__device__ __forceinline__ short8 cvt8(f32x4 a, f32x4 b) {
    u32x4 t;
    t[0] = pk2(a[0], a[1]);
    t[1] = pk2(a[2], a[3]);
    t[2] = pk2(b[0], b[1]);
    t[3] = pk2(b[2], b[3]);
    return __builtin_bit_cast(short8, t);
}

// async global->LDS, 16 B per lane. LDS dest is wave-uniform base + lane*16.
__device__ __forceinline__ void load_lds16(const float* g, float* l) {
    __builtin_amdgcn_global_load_lds(
        (const __attribute__((address_space(1))) void*)g,
        (__attribute__((address_space(3))) void*)l, 16, 0, 0);
}

// chunk id = floor(e / 10000) via magic mul: verified exact for e < 100000.
#define CHUNKOF(e) __umulhi((unsigned)(e), 429497u)

// ---------------------------------------------------------------------------
// Kernel 0: W [DIN][DOUT] f32  ->  Wt [DOUT][DIN] bf16 (transposed + converted)
// ---------------------------------------------------------------------------
__global__ void wt_conv(const float* __restrict__ W, unsigned short* __restrict__ Wt) {
    int t = blockIdx.x * 256 + threadIdx.x;   // 0 .. 32767
    int d = t >> 8;                           // dout
    int k = t & 255;                          // din
    float v = W[(size_t)k * DOUT + d];
    Wt[t] = (unsigned short)(pk2(v, v) & 0xffffu);
}

// ---------------------------------------------------------------------------
// Kernel 1: h = relu(feats @ W + b), bf16 row-major [n][128].  (R8 version.)
// ---------------------------------------------------------------------------
__global__ __launch_bounds__(256, 4) void gemm_relu(
        const float* __restrict__ feats, const unsigned short* __restrict__ Wt,
        const float* __restrict__ bias, unsigned short* __restrict__ h) {
    __shared__ float sf[32 * DIN];            // 32 KB: 32 node rows x 256 f32

    const int tid  = threadIdx.x;
    const int lane = tid & 63;
    const int w    = tid >> 6;                // wave = dout group
    const int l16  = lane & 15;
    const int lq   = lane >> 4;
    const int blockBase = blockIdx.x * 32;    // 3125 * 32 == 100000 exactly

    short8 afrag[2][8];
    const unsigned short* wp = Wt + (size_t)(w * 32 + l16) * DIN + lq * 8;
    #pragma unroll
    for (int m = 0; m < 2; ++m)
        #pragma unroll
        for (int ks = 0; ks < 8; ++ks)
            afrag[m][ks] = *(const short8*)(wp + m * 16 * DIN + ks * 32);

    #pragma unroll
    for (int it = 0; it < 8; ++it) {
        int row = it * 4 + w;
        int cd  = lane;
        int cs  = cd ^ (row & 7);             // inverse-swizzled global source
        load_lds16(feats + (size_t)(blockBase + row) * DIN + cs * 4,
                   sf + it * 1024 + tid * 4);
    }

    asm volatile("s_waitcnt vmcnt(0)" ::: "memory");
    __syncthreads();

    f32x4 acc[2][2];
    acc[0][0] = (f32x4)0.f; acc[0][1] = (f32x4)0.f;
    acc[1][0] = (f32x4)0.f; acc[1][1] = (f32x4)0.f;

    #pragma unroll
    for (int ks = 0; ks < 8; ++ks) {
        short8 bf0, bf1;
        {
            const float* rbase = sf + (size_t)l16 * DIN;
            f32x4 x0 = *(const f32x4*)(rbase + ((ks * 8 + 2 * lq)     ^ (l16 & 7)) * 4);
            f32x4 x1 = *(const f32x4*)(rbase + ((ks * 8 + 2 * lq + 1) ^ (l16 & 7)) * 4);
            bf0 = cvt8(x0, x1);
        }
        {
            const float* rbase = sf + (size_t)(16 + l16) * DIN;
            f32x4 x0 = *(const f32x4*)(rbase + ((ks * 8 + 2 * lq)     ^ (l16 & 7)) * 4);
            f32x4 x1 = *(const f32x4*)(rbase + ((ks * 8 + 2 * lq + 1) ^ (l16 & 7)) * 4);
            bf1 = cvt8(x0, x1);
        }
        #pragma unroll
        for (int m = 0; m < 2; ++m) {
            acc[m][0] = __builtin_amdgcn_mfma_f32_16x16x32_bf16(afrag[m][ks], bf0, acc[m][0], 0, 0, 0);
            acc[m][1] = __builtin_amdgcn_mfma_f32_16x16x32_bf16(afrag[m][ks], bf1, acc[m][1], 0, 0, 0);
        }
    }

    #pragma unroll
    for (int m = 0; m < 2; ++m) {
        int dbase = w * 32 + m * 16 + lq * 4;
        f32x4 bv = *(const f32x4*)(bias + dbase);
        #pragma unroll
        for (int nf = 0; nf < 2; ++nf) {
            int node = blockBase + nf * 16 + l16;
            f32x4 v = acc[m][nf];
            float v0 = fmaxf(v[0] + bv[0], 0.f);
            float v1 = fmaxf(v[1] + bv[1], 0.f);
            float v2 = fmaxf(v[2] + bv[2], 0.f);
            float v3 = fmaxf(v[3] + bv[3], 0.f);
            uint2 st = make_uint2(pk2(v0, v1), pk2(v2, v3));
            *(uint2*)(h + (size_t)node * DOUT + dbase) = st;
        }
    }
}

// ---------------------------------------------------------------------------
// Kernel S: per-node counting sort of the 32 edges by chunk id, plus packed
// 6-bit prefix offsets (u64) per node. One thread per node, all state in
// named registers / packed u64 (no runtime-indexed arrays - rule #20).
// ---------------------------------------------------------------------------
__global__ __launch_bounds__(256) void edge_sort(
        const int* __restrict__ edge, int* __restrict__ sorted,
        unsigned long long* __restrict__ pfx) {
    int n = blockIdx.x * 256 + threadIdx.x;
    if (n >= NN) return;
    const i32x4* ep = (const i32x4*)(edge + (size_t)n * KNB);
    i32x4 E0 = ep[0], E1 = ep[1], E2 = ep[2], E3 = ep[3];
    i32x4 E4 = ep[4], E5 = ep[5], E6 = ep[6], E7 = ep[7];

    unsigned long long cnt = 0;
    #define CNT1(e) (cnt += 1ULL << (6 * CHUNKOF(e)))
    #define CNT4(E) do { CNT1((E)[0]); CNT1((E)[1]); CNT1((E)[2]); CNT1((E)[3]); } while (0)
    CNT4(E0); CNT4(E1); CNT4(E2); CNT4(E3); CNT4(E4); CNT4(E5); CNT4(E6); CNT4(E7);
    #undef CNT4
    #undef CNT1

    unsigned long long off = 0;
    unsigned run = 0;
    #pragma unroll
    for (int c = 0; c < NCHUNK; ++c) {        // static -> static shifts
        off |= (unsigned long long)run << (6 * c);
        run += (unsigned)((cnt >> (6 * c)) & 63ULL);
    }
    pfx[n] = off;

    int* sp = sorted + (size_t)n * KNB;
    #define PUT1(e) do { unsigned c_ = CHUNKOF(e); \
        sp[(unsigned)((off >> (6 * c_)) & 63ULL)] = (e); \
        off += 1ULL << (6 * c_); } while (0)
    #define PUT4(E) do { PUT1((E)[0]); PUT1((E)[1]); PUT1((E)[2]); PUT1((E)[3]); } while (0)
    PUT4(E0); PUT4(E1); PUT4(E2); PUT4(E3); PUT4(E4); PUT4(E5); PUT4(E6); PUT4(E7);
    #undef PUT4
    #undef PUT1
}

// ---------------------------------------------------------------------------
// Kernel 2: chunk-phased gather over SORTED edges.
// R10 layout (1250 persistent blocks = all co-resident -> lockstep chunk
// sweep, FETCH 112 MB proven) but the per-chunk scaffold is now a dense walk
// j in [pfx[c], pfx[c+1]) of the sorted list: no shfl, no membership tests.
// Quarter-wave per node (q = dout octet), 5 batches x 8 f32 acc in named regs.
// Residual cost: exec-mask inflation across the wave's 4 node-groups (~1.9x
// on inner iterations only).
// ---------------------------------------------------------------------------
__global__ __launch_bounds__(256) void gather_sorted(
        const int* __restrict__ sorted, const unsigned long long* __restrict__ pfx,
        const unsigned short* __restrict__ h, float* __restrict__ out) {
    const int q = threadIdx.x & 15;
    const int g = threadIdx.x >> 4;           // node slot 0..15 within a batch
    const int nodeBase = blockIdx.x * 80;     // 1250 * 80 == 100000 exactly

    const int n0 = nodeBase + g;
    unsigned long long p0 = pfx[n0];
    unsigned long long p1 = pfx[n0 + 16];
    unsigned long long p2 = pfx[n0 + 32];
    unsigned long long p3 = pfx[n0 + 48];
    unsigned long long p4 = pfx[n0 + 64];

    f32x4 lo0 = (f32x4)0.f, hi0 = (f32x4)0.f;
    f32x4 lo1 = (f32x4)0.f, hi1 = (f32x4)0.f;
    f32x4 lo2 = (f32x4)0.f, hi2 = (f32x4)0.f;
    f32x4 lo3 = (f32x4)0.f, hi3 = (f32x4)0.f;
    f32x4 lo4 = (f32x4)0.f, hi4 = (f32x4)0.f;

    #define RUNB(NODE, P, LO, HI) do { \
        int st_ = (int)((P >> (6 * c)) & 63ULL); \
        int en_ = (c < NCHUNK - 1) ? (int)((P >> (6 * c + 6)) & 63ULL) : KNB; \
        const int* sp_ = sorted + (size_t)(NODE) * KNB; \
        for (int j = st_; j < en_; ++j) { \
            int e_ = sp_[j]; \
            u32x4 v_ = *(const u32x4*)(h + (size_t)e_ * DOUT + q * 8); \
            LO[0] += __uint_as_float(v_[0] << 16); \
            LO[1] += __uint_as_float(v_[0] & 0xffff0000u); \
            LO[2] += __uint_as_float(v_[1] << 16); \
            LO[3] += __uint_as_float(v_[1] & 0xffff0000u); \
            HI[0] += __uint_as_float(v_[2] << 16); \
            HI[1] += __uint_as_float(v_[2] & 0xffff0000u); \
            HI[2] += __uint_as_float(v_[3] << 16); \
            HI[3] += __uint_as_float(v_[3] & 0xffff0000u); \
        } } while (0)

    #pragma unroll 1
    for (int c = 0; c < NCHUNK; ++c) {
        RUNB(n0,      p0, lo0, hi0);
        RUNB(n0 + 16, p1, lo1, hi1);
        RUNB(n0 + 32, p2, lo2, hi2);
        RUNB(n0 + 48, p3, lo3, hi3);
        RUNB(n0 + 64, p4, lo4, hi4);
    }
    #undef RUNB

    const float sc = 1.f / KNB;
    #define STORE(B, LO, HI) do { \
        float* op_ = out + (size_t)(nodeBase + (B) * 16 + g) * DOUT + q * 8; \
        f32x4 o0_ = { LO[0] * sc, LO[1] * sc, LO[2] * sc, LO[3] * sc }; \
        f32x4 o1_ = { HI[0] * sc, HI[1] * sc, HI[2] * sc, HI[3] * sc }; \
        __builtin_nontemporal_store(o0_, (f32x4*)op_); \
        __builtin_nontemporal_store(o1_, (f32x4*)(op_ + 4)); } while (0)

    STORE(0, lo0, hi0);
    STORE(1, lo1, hi1);
    STORE(2, lo2, hi2);
    STORE(3, lo3, hi3);
    STORE(4, lo4, hi4);
    #undef STORE
}

// ---------------------------------------------------------------------------
// Fallback gather (R5, 107 µs) if ws can't hold sorted+pfx.
// ---------------------------------------------------------------------------
__global__ __launch_bounds__(256) void gather_mean(
        const int* __restrict__ edge, const unsigned short* __restrict__ h,
        float* __restrict__ out) {
    const int q = threadIdx.x & 15;
    const int n = blockIdx.x * 16 + (threadIdx.x >> 4);

    i32x2 e2 = __builtin_nontemporal_load((const i32x2*)(edge + (size_t)n * KNB + q * 2));

    float s0=0,s1=0,s2=0,s3=0,s4=0,s5=0,s6=0,s7=0;

    #define ROW(k) ((size_t)((k) < 16 ? __shfl(e2[0], (k), 16) \
                                      : __shfl(e2[1], (k) - 16, 16)) * DOUT)
    #define LD(k)  (*(const u32x4*)(h + ROW(k) + q * 8))
    #define ACC(v) do { \
        s0 += __uint_as_float((v)[0] << 16); \
        s1 += __uint_as_float((v)[0] & 0xffff0000u); \
        s2 += __uint_as_float((v)[1] << 16); \
        s3 += __uint_as_float((v)[1] & 0xffff0000u); \
        s4 += __uint_as_float((v)[2] << 16); \
        s5 += __uint_as_float((v)[2] & 0xffff0000u); \
        s6 += __uint_as_float((v)[3] << 16); \
        s7 += __uint_as_float((v)[3] & 0xffff0000u); } while (0)
    #define STEP(k, B) do { u32x4 v_ = (B); \
        if ((k) + 8 < KNB) (B) = LD((k) + 8); \
        ACC(v_); } while (0)

    u32x4 b0 = LD(0), b1 = LD(1), b2 = LD(2), b3 = LD(3);
    u32x4 b4 = LD(4), b5 = LD(5), b6 = LD(6), b7 = LD(7);

    STEP( 0, b0); STEP( 1, b1); STEP( 2, b2); STEP( 3, b3);
    STEP( 4, b4); STEP( 5, b5); STEP( 6, b6); STEP( 7, b7);
    STEP( 8, b0); STEP( 9, b1); STEP(10, b2); STEP(11, b3);
    STEP(12, b4); STEP(13, b5); STEP(14, b6); STEP(15, b7);
    STEP(16, b0); STEP(17, b1); STEP(18, b2); STEP(19, b3);
    STEP(20, b4); STEP(21, b5); STEP(22, b6); STEP(23, b7);
    STEP(24, b0); STEP(25, b1); STEP(26, b2); STEP(27, b3);
    STEP(28, b4); STEP(29, b5); STEP(30, b6); STEP(31, b7);

    #undef STEP
    #undef ACC
    #undef LD
    #undef ROW

    const float sc = 1.f / KNB;
    f32x4 o0 = { s0 * sc, s1 * sc, s2 * sc, s3 * sc };
    f32x4 o1 = { s4 * sc, s5 * sc, s6 * sc, s7 * sc };
    float* op = out + (size_t)n * DOUT + q * 8;
    __builtin_nontemporal_store(o0, (f32x4*)op);
    __builtin_nontemporal_store(o1, (f32x4*)(op + 4));
}

// ---------------------------------------------------------------------------
extern "C" void kernel_launch(void* const* d_in, const int* in_sizes, int n_in,
                              void* d_out, int out_size, void* d_ws, size_t ws_size,
                              hipStream_t stream) {
    const float* feats = (const float*)d_in[0];   // [100000,256] f32
    const int*   edge  = (const int*)d_in[1];     // [100000,32] i32
    const float* W     = (const float*)d_in[2];   // [256,128] f32
    const float* b     = (const float*)d_in[3];   // [128] f32
    float* out = (float*)d_out;                   // [100000,128] f32

    unsigned short* Wt = (unsigned short*)d_ws;                         // 64 KB
    unsigned short* h  = (unsigned short*)((char*)d_ws + 65536);        // 25.6 MB
    const size_t sortedOff = 65536 + (size_t)NN * DOUT * 2;             // 25,665,536
    const size_t pfxOff    = sortedOff + (size_t)NN * KNB * 4;          // 38,465,536
    const size_t need      = pfxOff + (size_t)NN * 8;                   // 39,265,536

    wt_conv<<<128, 256, 0, stream>>>(W, Wt);
    gemm_relu<<<NN / 32, 256, 0, stream>>>(feats, Wt, b, h);

    if (ws_size >= need) {
        int* sorted = (int*)((char*)d_ws + sortedOff);
        unsigned long long* pfx = (unsigned long long*)((char*)d_ws + pfxOff);
        edge_sort<<<(NN + 255) / 256, 256, 0, stream>>>(edge, sorted, pfx);
        gather_sorted<<<NN / 80, 256, 0, stream>>>(sorted, pfx, h, out);
    } else {
        gather_mean<<<NN / 16, 256, 0, stream>>>(edge, h, out);
    }
}

// Round 12
// 138.361 us; speedup vs baseline: 2.1226x; 1.6777x over previous
//
#include <hip/hip_runtime.h>
#include <hip/hip_bf16.h>

#define NN   100000
#define KNB  32
#define DIN  256
#define DOUT 128
#define NT   (NN / 32)        // 3125 gemm tiles of 32 nodes
#define GEMM_GRID 512         // persistent blocks, 2 per CU

typedef __attribute__((ext_vector_type(8))) short short8;    // 8 x bf16
typedef __attribute__((ext_vector_type(4))) float f32x4;     // 4 x f32
typedef __attribute__((ext_vector_type(4))) unsigned u32x4;  // 16 B
typedef __attribute__((ext_vector_type(2))) int i32x2;       // 8 B

// v_cvt_pk_bf16_f32: packs 2 f32 -> 2 bf16 (RTNE) in one VALU op (no builtin).
__device__ __forceinline__ unsigned pk2(float a, float b) {
    unsigned r;
    asm("v_cvt_pk_bf16_f32 %0, %1, %2" : "=v"(r) : "v"(a), "v"(b));
    return r;
}

__device__ __forceinline__ short8 cvt8(f32x4 a, f32x4 b) {
    u32x4 t;
    t[0] = pk2(a[0], a[1]);
    t[1] = pk2(a[2], a[3]);
    t[2] = pk2(b[0], b[1]);
    t[3] = pk2(b[2], b[3]);
    return __builtin_bit_cast(short8, t);
}

// async global->LDS, 16 B per lane. LDS dest is wave-uniform base + lane*16.
__device__ __forceinline__ void load_lds16(const float* g, float* l) {
    __builtin_amdgcn_global_load_lds(
        (const __attribute__((address_space(1))) void*)g,
        (__attribute__((address_space(3))) void*)l, 16, 0, 0);
}

// ---------------------------------------------------------------------------
// Kernel 0: W [DIN][DOUT] f32  ->  Wt [DOUT][DIN] bf16 (transposed + converted)
// ---------------------------------------------------------------------------
__global__ void wt_conv(const float* __restrict__ W, unsigned short* __restrict__ Wt) {
    int t = blockIdx.x * 256 + threadIdx.x;   // 0 .. 32767
    int d = t >> 8;                           // dout
    int k = t & 255;                          // din
    float v = W[(size_t)k * DOUT + d];
    Wt[t] = (unsigned short)(pk2(v, v) & 0xffffu);
}

// ---------------------------------------------------------------------------
// Kernel 1: h = relu(feats @ W + b), bf16 row-major [n][128].
// PERSISTENT 2-phase double-buffered pipeline (catalog T3-minimum):
//   - 512 blocks (2/CU, 64 KB LDS each), each sweeps ~6 tiles of 32 nodes.
//   - Wt fragments (16 KB -> 64 VGPR) + bias loaded ONCE per block,
//     amortized over all its tiles (R11 theory: per-block serial prologue
//     was the 40 µs cost; R6 proved the non-pipelined form latency-bound).
//   - Per tile: stage(next, buf^1) -> s_waitcnt vmcnt(8) [counted: the 8
//     newest outstanding = next-tile loads stay in flight] -> barrier ->
//     compute(cur) -> barrier. Staging always overlaps compute.
//   - launch_bounds(256,2): VGPR cap 256, no spill risk (R8 used (256,4)
//     with afrag 64 + acc 16 + temps right at the 128 boundary).
// Both-sides XOR swizzle (rule #21): chunk ^= row&7 on global source during
// staging and on the ds_read address (R8-verified pair, absmax unchanged).
// Operand-swapped MFMA: A = Wt (M = douts), B = feats^T (N = nodes).
// ---------------------------------------------------------------------------
__global__ __launch_bounds__(256, 2) void gemm_relu(
        const float* __restrict__ feats, const unsigned short* __restrict__ Wt,
        const float* __restrict__ bias, unsigned short* __restrict__ h) {
    __shared__ float sbuf[2][32 * DIN];       // 2 x 32 KB

    const int tid  = threadIdx.x;
    const int lane = tid & 63;
    const int w    = tid >> 6;                // wave = dout group
    const int l16  = lane & 15;
    const int lq   = lane >> 4;

    // Per-block constants: Wt fragments for this wave's 32 douts + bias.
    short8 afrag[2][8];
    const unsigned short* wp = Wt + (size_t)(w * 32 + l16) * DIN + lq * 8;
    #pragma unroll
    for (int m = 0; m < 2; ++m)
        #pragma unroll
        for (int ks = 0; ks < 8; ++ks)
            afrag[m][ks] = *(const short8*)(wp + m * 16 * DIN + ks * 32);

    f32x4 bv0 = *(const f32x4*)(bias + w * 32 + lq * 4);
    f32x4 bv1 = *(const f32x4*)(bias + w * 32 + 16 + lq * 4);

    // Stage one 32-node tile (32 KB) into sbuf[pb]; 8 x global_load_lds/wave.
    // Thread tid -> dest bytes it*4096 + tid*16 (lane-linear per wave): row =
    // it*4 + w, dest chunk cd = lane (64 x 16 B chunks per 1 KB row).
    auto stage = [&](int tile, int pb) {
        #pragma unroll
        for (int it = 0; it < 8; ++it) {
            int row = it * 4 + w;
            int cs  = lane ^ (row & 7);       // inverse-swizzled global source
            load_lds16(feats + (size_t)(tile * 32 + row) * DIN + cs * 4,
                       &sbuf[pb][it * 1024 + tid * 4]);
        }
    };

    int t  = blockIdx.x;
    if (t >= NT) return;
    stage(t, 0);
    int pb = 0;

    for (; t < NT; t += GEMM_GRID) {
        int tn = t + GEMM_GRID;
        if (tn < NT) {
            stage(tn, pb ^ 1);                // 8 newest vmem ops = next tile
            asm volatile("s_waitcnt vmcnt(8)" ::: "memory");  // cur tile ready
        } else {
            asm volatile("s_waitcnt vmcnt(0)" ::: "memory");
        }
        __syncthreads();

        f32x4 acc[2][2];
        acc[0][0] = (f32x4)0.f; acc[0][1] = (f32x4)0.f;
        acc[1][0] = (f32x4)0.f; acc[1][1] = (f32x4)0.f;

        const float* buf = sbuf[pb];
        #pragma unroll
        for (int ks = 0; ks < 8; ++ks) {
            short8 bf0, bf1;
            {
                const float* rbase = buf + (size_t)l16 * DIN;
                f32x4 x0 = *(const f32x4*)(rbase + ((ks * 8 + 2 * lq)     ^ (l16 & 7)) * 4);
                f32x4 x1 = *(const f32x4*)(rbase + ((ks * 8 + 2 * lq + 1) ^ (l16 & 7)) * 4);
                bf0 = cvt8(x0, x1);
            }
            {
                const float* rbase = buf + (size_t)(16 + l16) * DIN;
                f32x4 x0 = *(const f32x4*)(rbase + ((ks * 8 + 2 * lq)     ^ (l16 & 7)) * 4);
                f32x4 x1 = *(const f32x4*)(rbase + ((ks * 8 + 2 * lq + 1) ^ (l16 & 7)) * 4);
                bf1 = cvt8(x0, x1);
            }
            #pragma unroll
            for (int m = 0; m < 2; ++m) {
                acc[m][0] = __builtin_amdgcn_mfma_f32_16x16x32_bf16(afrag[m][ks], bf0, acc[m][0], 0, 0, 0);
                acc[m][1] = __builtin_amdgcn_mfma_f32_16x16x32_bf16(afrag[m][ks], bf1, acc[m][1], 0, 0, 0);
            }
        }

        // Epilogue: bias + relu + pack; wave writes its 32-dout stripe.
        // D layout: col (node) = lane&15, row (dout) = (lane>>4)*4 + reg [m89]
        #pragma unroll
        for (int m = 0; m < 2; ++m) {
            int dbase = w * 32 + m * 16 + lq * 4;
            f32x4 bv = (m == 0) ? bv0 : bv1;
            #pragma unroll
            for (int nf = 0; nf < 2; ++nf) {
                int node = t * 32 + nf * 16 + l16;
                f32x4 v = acc[m][nf];
                float v0 = fmaxf(v[0] + bv[0], 0.f);
                float v1 = fmaxf(v[1] + bv[1], 0.f);
                float v2 = fmaxf(v[2] + bv[2], 0.f);
                float v3 = fmaxf(v[3] + bv[3], 0.f);
                uint2 st = make_uint2(pk2(v0, v1), pk2(v2, v3));
                *(uint2*)(h + (size_t)node * DOUT + dbase) = st;
            }
        }

        __syncthreads();                      // buf free for next stage
        pb ^= 1;
    }
}

// ---------------------------------------------------------------------------
// Kernel 2: out[n] = mean_k h_bf16[edge[n][k]]   (R5 form, 107 µs — pinned at
// ~3.8 TB/s beyond-L2 fill across 5 structural variants; chunked/sorted
// variants cut FETCH 343->112/196 MB but lost more to scaffold/divergence
// (R10: +150 µs VALU; R11: dependent-chain MLP collapse). This is the
// execution-optimal form.)
// ---------------------------------------------------------------------------
__global__ __launch_bounds__(256) void gather_mean(
        const int* __restrict__ edge, const unsigned short* __restrict__ h,
        float* __restrict__ out) {
    const int q = threadIdx.x & 15;
    const int n = blockIdx.x * 16 + (threadIdx.x >> 4);   // 6250*16 == NN

    i32x2 e2 = __builtin_nontemporal_load((const i32x2*)(edge + (size_t)n * KNB + q * 2));

    float s0=0,s1=0,s2=0,s3=0,s4=0,s5=0,s6=0,s7=0;

    #define ROW(k) ((size_t)((k) < 16 ? __shfl(e2[0], (k), 16) \
                                      : __shfl(e2[1], (k) - 16, 16)) * DOUT)
    #define LD(k)  (*(const u32x4*)(h + ROW(k) + q * 8))
    #define ACC(v) do { \
        s0 += __uint_as_float((v)[0] << 16); \
        s1 += __uint_as_float((v)[0] & 0xffff0000u); \
        s2 += __uint_as_float((v)[1] << 16); \
        s3 += __uint_as_float((v)[1] & 0xffff0000u); \
        s4 += __uint_as_float((v)[2] << 16); \
        s5 += __uint_as_float((v)[2] & 0xffff0000u); \
        s6 += __uint_as_float((v)[3] << 16); \
        s7 += __uint_as_float((v)[3] & 0xffff0000u); } while (0)
    #define STEP(k, B) do { u32x4 v_ = (B); \
        if ((k) + 8 < KNB) (B) = LD((k) + 8); \
        ACC(v_); } while (0)

    u32x4 b0 = LD(0), b1 = LD(1), b2 = LD(2), b3 = LD(3);
    u32x4 b4 = LD(4), b5 = LD(5), b6 = LD(6), b7 = LD(7);

    STEP( 0, b0); STEP( 1, b1); STEP( 2, b2); STEP( 3, b3);
    STEP( 4, b4); STEP( 5, b5); STEP( 6, b6); STEP( 7, b7);
    STEP( 8, b0); STEP( 9, b1); STEP(10, b2); STEP(11, b3);
    STEP(12, b4); STEP(13, b5); STEP(14, b6); STEP(15, b7);
    STEP(16, b0); STEP(17, b1); STEP(18, b2); STEP(19, b3);
    STEP(20, b4); STEP(21, b5); STEP(22, b6); STEP(23, b7);
    STEP(24, b0); STEP(25, b1); STEP(26, b2); STEP(27, b3);
    STEP(28, b4); STEP(29, b5); STEP(30, b6); STEP(31, b7);

    #undef STEP
    #undef ACC
    #undef LD
    #undef ROW

    const float sc = 1.f / KNB;
    f32x4 o0 = { s0 * sc, s1 * sc, s2 * sc, s3 * sc };
    f32x4 o1 = { s4 * sc, s5 * sc, s6 * sc, s7 * sc };
    float* op = out + (size_t)n * DOUT + q * 8;
    __builtin_nontemporal_store(o0, (f32x4*)op);
    __builtin_nontemporal_store(o1, (f32x4*)(op + 4));
}

// ---------------------------------------------------------------------------
extern "C" void kernel_launch(void* const* d_in, const int* in_sizes, int n_in,
                              void* d_out, int out_size, void* d_ws, size_t ws_size,
                              hipStream_t stream) {
    const float* feats = (const float*)d_in[0];   // [100000,256] f32
    const int*   edge  = (const int*)d_in[1];     // [100000,32] i32
    const float* W     = (const float*)d_in[2];   // [256,128] f32
    const float* b     = (const float*)d_in[3];   // [128] f32
    float* out = (float*)d_out;                   // [100000,128] f32

    unsigned short* Wt = (unsigned short*)d_ws;                    // 64 KB
    unsigned short* h  = (unsigned short*)((char*)d_ws + 65536);   // 25.6 MB

    wt_conv<<<128, 256, 0, stream>>>(W, Wt);
    gemm_relu<<<GEMM_GRID, 256, 0, stream>>>(feats, Wt, b, h);
    gather_mean<<<NN / 16, 256, 0, stream>>>(edge, h, out);
}

// Round 13
// 133.931 us; speedup vs baseline: 2.1928x; 1.0331x over previous
//
#include <hip/hip_runtime.h>
#include <hip/hip_bf16.h>

#define NN   100000
#define KNB  32
#define DIN  256
#define DOUT 128
#define NT   (NN / 32)        // 3125 gemm tiles of 32 nodes
#define GEMM_GRID 512         // persistent blocks, 2 per CU (64 KB LDS each)

typedef __attribute__((ext_vector_type(8))) short short8;    // 8 x bf16
typedef __attribute__((ext_vector_type(4))) float f32x4;     // 4 x f32
typedef __attribute__((ext_vector_type(4))) unsigned u32x4;  // 16 B
typedef __attribute__((ext_vector_type(2))) int i32x2;       // 8 B

// v_cvt_pk_bf16_f32: packs 2 f32 -> 2 bf16 (RTNE) in one VALU op (no builtin).
__device__ __forceinline__ unsigned pk2(float a, float b) {
    unsigned r;
    asm("v_cvt_pk_bf16_f32 %0, %1, %2" : "=v"(r) : "v"(a), "v"(b));
    return r;
}

__device__ __forceinline__ short8 cvt8(f32x4 a, f32x4 b) {
    u32x4 t;
    t[0] = pk2(a[0], a[1]);
    t[1] = pk2(a[2], a[3]);
    t[2] = pk2(b[0], b[1]);
    t[3] = pk2(b[2], b[3]);
    return __builtin_bit_cast(short8, t);
}

// async global->LDS, 16 B per lane. LDS dest is wave-uniform base + lane*16.
__device__ __forceinline__ void load_lds16(const float* g, float* l) {
    __builtin_amdgcn_global_load_lds(
        (const __attribute__((address_space(1))) void*)g,
        (__attribute__((address_space(3))) void*)l, 16, 0, 0);
}

// ---------------------------------------------------------------------------
// Kernel 1: h = relu(feats @ W + b), bf16 row-major [n][128].
// R12 persistent 2-phase double-buffered pipeline (landed at ~25 µs, 81% of
// achievable BW), now with wt_conv FUSED into the block prologue: each wave
// builds its 32-dout Wt slice directly from W via 128 scalar column reads
// (strided, but W is L2-resident after the first blocks per XCD; once per
// block, amortized over ~6 tiles). Bit-identical to the old wt_conv path.
// Per tile: stage(next, buf^1) -> s_waitcnt vmcnt(8) [counted, never 0
// mid-loop] -> barrier -> compute(cur) -> store -> barrier.
// Both-sides XOR swizzle (rule #21): chunk ^= row&7 on the global source at
// staging and on the ds_read address.
// Operand-swapped MFMA: A = Wt (M = douts), B = feats^T (N = nodes).
// D layout: col (node) = lane&15, row (dout) = (lane>>4)*4 + reg  [m89]
// ---------------------------------------------------------------------------
__global__ __launch_bounds__(256, 2) void gemm_relu(
        const float* __restrict__ feats, const float* __restrict__ W,
        const float* __restrict__ bias, unsigned short* __restrict__ h) {
    __shared__ float sbuf[2][32 * DIN];       // 2 x 32 KB

    const int tid  = threadIdx.x;
    const int lane = tid & 63;
    const int w    = tid >> 6;                // wave = dout group
    const int l16  = lane & 15;
    const int lq   = lane >> 4;

    // Prologue (once per block): build Wt fragments for this wave's 32 douts
    // straight from W [DIN][DOUT] f32. afrag[m][ks] element j must equal
    // bf16(W[ks*32 + lq*8 + j][w*32 + m*16 + l16])  — same values the old
    // wt_conv produced (pk2 pairs j=2p, 2p+1).
    short8 afrag[2][8];
    {
        const float* wbase = W + w * 32 + l16;
        #pragma unroll
        for (int m = 0; m < 2; ++m) {
            #pragma unroll
            for (int ks = 0; ks < 8; ++ks) {
                const float* wcol = wbase + (size_t)(ks * 32 + lq * 8) * DOUT + m * 16;
                u32x4 t;
                #pragma unroll
                for (int p = 0; p < 4; ++p) {
                    float a = wcol[(size_t)(2 * p)     * DOUT];
                    float b = wcol[(size_t)(2 * p + 1) * DOUT];
                    t[p] = pk2(a, b);
                }
                afrag[m][ks] = __builtin_bit_cast(short8, t);
            }
        }
    }

    f32x4 bv0 = *(const f32x4*)(bias + w * 32 + lq * 4);
    f32x4 bv1 = *(const f32x4*)(bias + w * 32 + 16 + lq * 4);

    // Stage one 32-node tile (32 KB) into sbuf[pb]; 8 x global_load_lds/wave.
    auto stage = [&](int tile, int pb) {
        #pragma unroll
        for (int it = 0; it < 8; ++it) {
            int row = it * 4 + w;
            int cs  = lane ^ (row & 7);       // inverse-swizzled global source
            load_lds16(feats + (size_t)(tile * 32 + row) * DIN + cs * 4,
                       &sbuf[pb][it * 1024 + tid * 4]);
        }
    };

    int t = blockIdx.x;
    if (t >= NT) return;
    stage(t, 0);
    int pb = 0;

    for (; t < NT; t += GEMM_GRID) {
        int tn = t + GEMM_GRID;
        if (tn < NT) {
            stage(tn, pb ^ 1);                // 8 newest vmem ops = next tile
            asm volatile("s_waitcnt vmcnt(8)" ::: "memory");  // cur tile ready
        } else {
            asm volatile("s_waitcnt vmcnt(0)" ::: "memory");
        }
        __syncthreads();

        f32x4 acc[2][2];
        acc[0][0] = (f32x4)0.f; acc[0][1] = (f32x4)0.f;
        acc[1][0] = (f32x4)0.f; acc[1][1] = (f32x4)0.f;

        const float* buf = sbuf[pb];
        #pragma unroll
        for (int ks = 0; ks < 8; ++ks) {
            short8 bf0, bf1;
            {
                const float* rbase = buf + (size_t)l16 * DIN;
                f32x4 x0 = *(const f32x4*)(rbase + ((ks * 8 + 2 * lq)     ^ (l16 & 7)) * 4);
                f32x4 x1 = *(const f32x4*)(rbase + ((ks * 8 + 2 * lq + 1) ^ (l16 & 7)) * 4);
                bf0 = cvt8(x0, x1);
            }
            {
                const float* rbase = buf + (size_t)(16 + l16) * DIN;
                f32x4 x0 = *(const f32x4*)(rbase + ((ks * 8 + 2 * lq)     ^ (l16 & 7)) * 4);
                f32x4 x1 = *(const f32x4*)(rbase + ((ks * 8 + 2 * lq + 1) ^ (l16 & 7)) * 4);
                bf1 = cvt8(x0, x1);
            }
            #pragma unroll
            for (int m = 0; m < 2; ++m) {
                acc[m][0] = __builtin_amdgcn_mfma_f32_16x16x32_bf16(afrag[m][ks], bf0, acc[m][0], 0, 0, 0);
                acc[m][1] = __builtin_amdgcn_mfma_f32_16x16x32_bf16(afrag[m][ks], bf1, acc[m][1], 0, 0, 0);
            }
        }

        #pragma unroll
        for (int m = 0; m < 2; ++m) {
            int dbase = w * 32 + m * 16 + lq * 4;
            f32x4 bv = (m == 0) ? bv0 : bv1;
            #pragma unroll
            for (int nf = 0; nf < 2; ++nf) {
                int node = t * 32 + nf * 16 + l16;
                f32x4 v = acc[m][nf];
                float v0 = fmaxf(v[0] + bv[0], 0.f);
                float v1 = fmaxf(v[1] + bv[1], 0.f);
                float v2 = fmaxf(v[2] + bv[2], 0.f);
                float v3 = fmaxf(v[3] + bv[3], 0.f);
                uint2 st = make_uint2(pk2(v0, v1), pk2(v2, v3));
                *(uint2*)(h + (size_t)node * DOUT + dbase) = st;
            }
        }

        __syncthreads();                      // buf free for next stage
        pb ^= 1;
    }
}

// ---------------------------------------------------------------------------
// Kernel 2: out[n] = mean_k h_bf16[edge[n][k]]   (R5 form, 107 µs — pinned at
// ~3.8 TB/s beyond-L2 fill across 6 structural variants; traffic-reduction
// scaffolds (chunked/sorted) cut FETCH 343->112/196 MB but lost more to
// VALU/divergence/dependent-chain serialization. Execution-optimal form.)
// ---------------------------------------------------------------------------
__global__ __launch_bounds__(256) void gather_mean(
        const int* __restrict__ edge, const unsigned short* __restrict__ h,
        float* __restrict__ out) {
    const int q = threadIdx.x & 15;
    const int n = blockIdx.x * 16 + (threadIdx.x >> 4);   // 6250*16 == NN

    i32x2 e2 = __builtin_nontemporal_load((const i32x2*)(edge + (size_t)n * KNB + q * 2));

    float s0=0,s1=0,s2=0,s3=0,s4=0,s5=0,s6=0,s7=0;

    #define ROW(k) ((size_t)((k) < 16 ? __shfl(e2[0], (k), 16) \
                                      : __shfl(e2[1], (k) - 16, 16)) * DOUT)
    #define LD(k)  (*(const u32x4*)(h + ROW(k) + q * 8))
    #define ACC(v) do { \
        s0 += __uint_as_float((v)[0] << 16); \
        s1 += __uint_as_float((v)[0] & 0xffff0000u); \
        s2 += __uint_as_float((v)[1] << 16); \
        s3 += __uint_as_float((v)[1] & 0xffff0000u); \
        s4 += __uint_as_float((v)[2] << 16); \
        s5 += __uint_as_float((v)[2] & 0xffff0000u); \
        s6 += __uint_as_float((v)[3] << 16); \
        s7 += __uint_as_float((v)[3] & 0xffff0000u); } while (0)
    #define STEP(k, B) do { u32x4 v_ = (B); \
        if ((k) + 8 < KNB) (B) = LD((k) + 8); \
        ACC(v_); } while (0)

    u32x4 b0 = LD(0), b1 = LD(1), b2 = LD(2), b3 = LD(3);
    u32x4 b4 = LD(4), b5 = LD(5), b6 = LD(6), b7 = LD(7);

    STEP( 0, b0); STEP( 1, b1); STEP( 2, b2); STEP( 3, b3);
    STEP( 4, b4); STEP( 5, b5); STEP( 6, b6); STEP( 7, b7);
    STEP( 8, b0); STEP( 9, b1); STEP(10, b2); STEP(11, b3);
    STEP(12, b4); STEP(13, b5); STEP(14, b6); STEP(15, b7);
    STEP(16, b0); STEP(17, b1); STEP(18, b2); STEP(19, b3);
    STEP(20, b4); STEP(21, b5); STEP(22, b6); STEP(23, b7);
    STEP(24, b0); STEP(25, b1); STEP(26, b2); STEP(27, b3);
    STEP(28, b4); STEP(29, b5); STEP(30, b6); STEP(31, b7);

    #undef STEP
    #undef ACC
    #undef LD
    #undef ROW

    const float sc = 1.f / KNB;
    f32x4 o0 = { s0 * sc, s1 * sc, s2 * sc, s3 * sc };
    f32x4 o1 = { s4 * sc, s5 * sc, s6 * sc, s7 * sc };
    float* op = out + (size_t)n * DOUT + q * 8;
    __builtin_nontemporal_store(o0, (f32x4*)op);
    __builtin_nontemporal_store(o1, (f32x4*)(op + 4));
}

// ---------------------------------------------------------------------------
extern "C" void kernel_launch(void* const* d_in, const int* in_sizes, int n_in,
                              void* d_out, int out_size, void* d_ws, size_t ws_size,
                              hipStream_t stream) {
    const float* feats = (const float*)d_in[0];   // [100000,256] f32
    const int*   edge  = (const int*)d_in[1];     // [100000,32] i32
    const float* W     = (const float*)d_in[2];   // [256,128] f32
    const float* b     = (const float*)d_in[3];   // [128] f32
    float* out = (float*)d_out;                   // [100000,128] f32

    unsigned short* h = (unsigned short*)d_ws;    // 25.6 MB bf16 row-major

    gemm_relu<<<GEMM_GRID, 256, 0, stream>>>(feats, W, b, h);
    gather_mean<<<NN / 16, 256, 0, stream>>>(edge, h, out);
}